// Round 1
// baseline (104.254 us; speedup 1.0000x reference)
//
#include <hip/hip_runtime.h>

typedef float    f32x4  __attribute__((ext_vector_type(4)));
typedef float    f32x16 __attribute__((ext_vector_type(16)));
typedef __bf16   bf16x8 __attribute__((ext_vector_type(8)));
typedef __bf16   bf16x2 __attribute__((ext_vector_type(2)));
typedef unsigned uint2v __attribute__((ext_vector_type(2)));

union Frag { unsigned u[4]; bf16x8 b; };

static __device__ __forceinline__ unsigned pack2(float a, float b) {
    bf16x2 t;
    t[0] = (__bf16)a;
    t[1] = (__bf16)b;
    return __builtin_bit_cast(unsigned, t);
}

static __device__ __forceinline__ unsigned short f2bfu(float x) {
    __bf16 b = (__bf16)x;
    return __builtin_bit_cast(unsigned short, b);
}

static __device__ __forceinline__ uint2v pswap(unsigned a, unsigned b) {
#if __has_builtin(__builtin_amdgcn_permlane32_swap)
    return __builtin_amdgcn_permlane32_swap(a, b, false, false);
#else
    unsigned ax = (unsigned)__shfl_xor((int)a, 32);
    unsigned bx = (unsigned)__shfl_xor((int)b, 32);
    bool lo = (__lane_id() & 32) == 0;
    uint2v r;
    r[0] = lo ? a : bx;
    r[1] = lo ? ax : b;
    return r;
#endif
}

// ---------------------------------------------------------------------------
// Preprocess: f32 -> bf16 weight conversion + fragment-order scatter.
//  w1bf : [20][64][16] bf16 (natural layout; lane reads 16B = 8 d-values)
//  w2f  : [20][f=0..7][lane=0..63][8] bf16, f = g_tile*4 + kk
//         value = W2[m][g=32*(f>>2)+(l&31)][h=16*(f&3)+8*(l>>5)+j]
//  b1f/b2f/w3f : [20][tile][half][16] f32 in MFMA C-fragment register order:
//         value i = src[m][32*tile + 4*half + (i&3) + 8*(i>>2)]
// ---------------------------------------------------------------------------
__global__ void prep_kernel(
    const float* __restrict__ W1, const float* __restrict__ W2,
    const float* __restrict__ b1, const float* __restrict__ b2,
    const float* __restrict__ W3,
    unsigned short* __restrict__ w1bf, unsigned short* __restrict__ w2f,
    float* __restrict__ b1f, float* __restrict__ b2f, float* __restrict__ w3f)
{
    const int t = blockIdx.x * 256 + threadIdx.x;
    if (t < 20480) w1bf[t] = f2bfu(W1[t]);
    if (t < 81920) {
        const int j = t & 7, l = (t >> 3) & 63, f = (t >> 9) & 7, m = t >> 12;
        const int g = 32 * (f >> 2) + (l & 31);
        const int h = 16 * (f & 3) + 8 * (l >> 5) + j;
        w2f[t] = f2bfu(W2[(m * 64 + g) * 64 + h]);
    }
    if (t < 1280) {
        const int i = t & 15, hf = (t >> 4) & 1, tt = (t >> 5) & 1, m = t >> 6;
        const int h = 32 * tt + 4 * hf + (i & 3) + 8 * (i >> 2);
        b1f[t] = b1[m * 64 + h];
        b2f[t] = b2[m * 64 + h];
        w3f[t] = W3[m * 64 + h];
    }
}

// ---------------------------------------------------------------------------
// Fused: per wave, 2 tiles x 32 events. All 20 MLPs via 32x32x16 bf16 MFMA in
// D[h][n] orientation (event = lane%32 everywhere). Layer1 D-frag -> Layer2
// B-frag via cvt_pk + permlane32_swap (no LDS). Layer3 + rho epilogue in f32.
// ---------------------------------------------------------------------------
__global__ __launch_bounds__(256, 2) void fused_kernel(
    const float* __restrict__ Data,
    const float* __restrict__ Parameters,
    const float* __restrict__ Shift,
    const float* __restrict__ Scaling,
    const float* __restrict__ PScal,
    const float* __restrict__ b3,
    const unsigned short* __restrict__ w1bf,
    const unsigned short* __restrict__ w2f,
    const float* __restrict__ b1f,
    const float* __restrict__ b2f,
    const float* __restrict__ w3f,
    float* __restrict__ rho)
{
    __shared__ float outl[8][32][28];   // [tile-in-block][event][m] (+pad: 28 floats -> 112B rows, 16B aligned)

    const int tid  = threadIdx.x;
    const int wave = tid >> 6;
    const int lane = tid & 63;
    const int ln   = lane & 31;
    const int half = lane >> 5;
    const int n0   = (blockIdx.x * 4 + wave) * 64;

    // x fragments (bf16) for this wave's two 32-event tiles. B-frag layout:
    // col n = lane%32, k d = 8*half + j.
    bf16x8 xf[2];
    #pragma unroll
    for (int e = 0; e < 2; ++e) {
        const float* dp = Data + (size_t)(n0 + e * 32 + ln) * 16 + 8 * half;
        f32x4 v0 = *(const f32x4*)dp;
        f32x4 v1 = *(const f32x4*)(dp + 4);
        float xv[8];
        #pragma unroll
        for (int j = 0; j < 4; ++j) {
            xv[j]     = (v0[j] - Shift[8 * half + j])     / Scaling[8 * half + j];
            xv[4 + j] = (v1[j] - Shift[8 * half + 4 + j]) / Scaling[8 * half + 4 + j];
        }
        Frag fx;
        #pragma unroll
        for (int c = 0; c < 4; ++c) fx.u[c] = pack2(xv[2 * c], xv[2 * c + 1]);
        xf[e] = fx.b;
    }

    for (int m = 0; m < 20; ++m) {
        // A-fragments: W1 rows (h = lane%32 + 32t, d = 8*half+j)
        bf16x8 a1[2];
        #pragma unroll
        for (int t = 0; t < 2; ++t)
            a1[t] = *(const bf16x8*)(w1bf + ((size_t)(m * 64 + 32 * t + ln) * 16 + 8 * half));
        // A-fragments: W2 rows (pre-scattered, fully coalesced 16B/lane)
        bf16x8 a2[8];
        #pragma unroll
        for (int f = 0; f < 8; ++f)
            a2[f] = *(const bf16x8*)(w2f + ((size_t)((m * 8 + f) * 64 + lane)) * 8);
        const float b3v = b3[m];

        #pragma unroll
        for (int e = 0; e < 2; ++e) {
            unsigned bfr[4][4];    // layer2 B-fragments [kk][4 dwords]
            #pragma unroll
            for (int t = 0; t < 2; ++t) {
                // acc init = b1 bias (C-fragment order)
                const f32x4* bp = (const f32x4*)(b1f + ((m * 2 + t) * 2 + half) * 16);
                f32x16 acc;
                #pragma unroll
                for (int q = 0; q < 4; ++q) {
                    f32x4 bq = bp[q];
                    #pragma unroll
                    for (int j = 0; j < 4; ++j) acc[4 * q + j] = bq[j];
                }
                acc = __builtin_amdgcn_mfma_f32_32x32x16_bf16(a1[t], xf[e], acc, 0, 0, 0);
                // relu + pack to bf16 pairs: p[q] holds h = {base, base+1}, rows
                // (2q&3)+8*(2q>>2)... i.e. q=0..7 -> h {0,1},{2,3},{8,9},{10,11},
                // {16,17},{18,19},{24,25},{26,27} (+4*half, +32t)
                unsigned p[8];
                #pragma unroll
                for (int q = 0; q < 8; ++q)
                    p[q] = pack2(fmaxf(acc[2 * q], 0.f), fmaxf(acc[2 * q + 1], 0.f));
                // lane-half exchange -> B-fragments for kk = 2t, 2t+1
                uint2v r0 = pswap(p[0], p[2]);
                uint2v r1 = pswap(p[1], p[3]);
                uint2v r2 = pswap(p[4], p[6]);
                uint2v r3 = pswap(p[5], p[7]);
                bfr[2 * t    ][0] = r0[0]; bfr[2 * t    ][1] = r1[0];
                bfr[2 * t    ][2] = r0[1]; bfr[2 * t    ][3] = r1[1];
                bfr[2 * t + 1][0] = r2[0]; bfr[2 * t + 1][1] = r3[0];
                bfr[2 * t + 1][2] = r2[1]; bfr[2 * t + 1][3] = r3[1];
            }
            // layer2 (g-tiles) + layer3 partial sums
            float sum = 0.f;
            #pragma unroll
            for (int tg = 0; tg < 2; ++tg) {
                const f32x4* bp = (const f32x4*)(b2f + ((m * 2 + tg) * 2 + half) * 16);
                f32x16 acc;
                #pragma unroll
                for (int q = 0; q < 4; ++q) {
                    f32x4 bq = bp[q];
                    #pragma unroll
                    for (int j = 0; j < 4; ++j) acc[4 * q + j] = bq[j];
                }
                #pragma unroll
                for (int kk = 0; kk < 4; ++kk) {
                    Frag fb;
                    #pragma unroll
                    for (int c = 0; c < 4; ++c) fb.u[c] = bfr[kk][c];
                    acc = __builtin_amdgcn_mfma_f32_32x32x16_bf16(a2[tg * 4 + kk], fb.b, acc, 0, 0, 0);
                }
                const f32x4* wp = (const f32x4*)(w3f + ((m * 2 + tg) * 2 + half) * 16);
                #pragma unroll
                for (int q = 0; q < 4; ++q) {
                    f32x4 wq = wp[q];
                    #pragma unroll
                    for (int j = 0; j < 4; ++j)
                        sum = fmaf(wq[j], fmaxf(acc[4 * q + j], 0.f), sum);
                }
            }
            sum += __shfl_xor(sum, 32);           // combine the two lane-halves
            if (lane < 32) outl[wave * 2 + e][lane][m] = sum + b3v;
        }
    }

    // ----- epilogue: rho[n,k] = sum_i (Mlt[n,i,:] . ParM[k,:])^2, k = lane -----
    const float pk1 = Parameters[lane * 5 + 0] / PScal[0];
    const float pk2 = Parameters[lane * 5 + 1] / PScal[1];
    const float pk3 = Parameters[lane * 5 + 2] / PScal[2];
    const float pk4 = Parameters[lane * 5 + 3] / PScal[3];
    const float pk5 = Parameters[lane * 5 + 4] / PScal[4];

    asm volatile("s_waitcnt lgkmcnt(0)" ::: "memory");  // wave-local LDS writes visible

    #pragma unroll
    for (int e = 0; e < 2; ++e) {
        const int tb = wave * 2 + e;
        #pragma unroll 4
        for (int np = 0; np < 32; ++np) {
            const f32x4* orow = (const f32x4*)&outl[tb][np][0];
            f32x4 oa = orow[0], ob = orow[1], oc = orow[2], od = orow[3], oe = orow[4];
            float m0 = 1.0f + oa[0] * pk1 + oa[1] * pk2 + oa[2] * pk3 + oa[3] * pk4 + ob[0] * pk5;
            float m1 = ob[1] * pk1 + ob[2] * pk2 + ob[3] * pk3 + oc[0] * pk4 + oc[1] * pk5;
            float m2 = oc[2] * pk2 + oc[3] * pk3 + od[0] * pk4 + od[1] * pk5;
            float m3 = od[2] * pk3 + od[3] * pk4 + oe[0] * pk5;
            float m4 = oe[1] * pk4 + oe[2] * pk5;
            float m5 = oe[3] * pk5;
            float r = m0 * m0 + m1 * m1 + m2 * m2 + m3 * m3 + m4 * m4 + m5 * m5;
            rho[(size_t)(n0 + e * 32 + np) * 64 + lane] = r;
        }
    }
}

extern "C" void kernel_launch(void* const* d_in, const int* in_sizes, int n_in,
                              void* d_out, int out_size, void* d_ws, size_t ws_size,
                              hipStream_t stream)
{
    const float* Data   = (const float*)d_in[0];
    const float* Params = (const float*)d_in[1];
    const float* Shift  = (const float*)d_in[2];
    const float* Scal   = (const float*)d_in[3];
    const float* PScal  = (const float*)d_in[4];
    const float* W1     = (const float*)d_in[5];
    const float* b1     = (const float*)d_in[6];
    const float* W2     = (const float*)d_in[7];
    const float* b2     = (const float*)d_in[8];
    const float* W3     = (const float*)d_in[9];
    const float* b3     = (const float*)d_in[10];
    float* rho = (float*)d_out;
    const int N = in_sizes[0] / 16;   // 131072

    char* ws = (char*)d_ws;
    unsigned short* w1bf = (unsigned short*)(ws);            //  40960 B
    unsigned short* w2f  = (unsigned short*)(ws + 40960);    // 163840 B
    float* b1f = (float*)(ws + 204800);                      //   5120 B
    float* b2f = (float*)(ws + 209920);                      //   5120 B
    float* w3f = (float*)(ws + 215040);                      //   5120 B

    prep_kernel<<<320, 256, 0, stream>>>(W1, W2, b1, b2, W3, w1bf, w2f, b1f, b2f, w3f);
    fused_kernel<<<N / 256, 256, 0, stream>>>(Data, Params, Shift, Scal, PScal, b3,
                                              w1bf, w2f, b1f, b2f, w3f, rho);
}